// Round 12
// baseline (121.754 us; speedup 1.0000x reference)
//
#include <hip/hip_runtime.h>
#include <hip/hip_bf16.h>

typedef __attribute__((ext_vector_type(8))) short bf16x8;
typedef __attribute__((ext_vector_type(4))) float f32x4;

#define U_LD 2176      // padded K (multiple of 64)
#define K_REAL 2145    // 33*65
#define DIM0 33
#define DIM1 33
#define DIM2 65
#define NROW 2048
#define OO 128

__device__ __forceinline__ unsigned short f2bf(float f) {
  union { float f; unsigned u; } v; v.f = f;
  unsigned r = v.u + 0x7fffu + ((v.u >> 16) & 1u);   // round-to-nearest-even
  return (unsigned short)(r >> 16);
}

#define GLOAD_LDS16(SRC, DST) \
  __builtin_amdgcn_global_load_lds((const __attribute__((address_space(1))) void*)(SRC), \
                                   (__attribute__((address_space(3))) void*)(DST), 16, 0, 0)

// ---- merged prep: blocks 0..1121 convert W -> Wt[a][o][k]; blocks 1122..3169
//      build U[n][k] = bf16(x1[n,b]*x2[n,c]). ----
__global__ __launch_bounds__(256) void prep_kernel(const float* __restrict__ x1,
                                                   const float* __restrict__ x2,
                                                   const float* __restrict__ W,
                                                   ushort* __restrict__ U,
                                                   ushort* __restrict__ Wt) {
  __shared__ ushort s[64][130];   // [k][o], pad to 130 to spread banks
  int bx = (int)blockIdx.x;
  int tid = threadIdx.x;
  if (bx < 34 * 33) {
    // ---- Wt slab: a = bx%33, k0 = (bx/33)*64 ----
    int a = bx % 33;
    int k0 = (bx / 33) * 64;
    for (int idx = tid; idx < 64 * 32; idx += 256) {
      int kk = idx >> 5;
      int og = (idx & 31) * 4;
      int k = k0 + kk;
      float4 v = make_float4(0.f, 0.f, 0.f, 0.f);
      if (k < K_REAL) {
        int b = k / DIM2; int c = k - b * DIM2;
        v = *(const float4*)&W[(((size_t)a * DIM1 + b) * DIM2 + c) * OO + og];
      }
      s[kk][og]     = f2bf(v.x);
      s[kk][og + 1] = f2bf(v.y);
      s[kk][og + 2] = f2bf(v.z);
      s[kk][og + 3] = f2bf(v.w);
    }
    __syncthreads();
    // store: thread o (<128) writes ONE aligned 128B cacheline: Wt[a][o][k0..k0+63]
    if (tid < OO) {
      int o = tid;
      union { ushort us[64]; uint4 v[8]; } pk;
#pragma unroll
      for (int j = 0; j < 64; ++j) pk.us[j] = s[j][o];
      uint4* dst = (uint4*)&Wt[((size_t)a * OO + o) * U_LD + k0];
#pragma unroll
      for (int q = 0; q < 8; ++q) dst[q] = pk.v[q];
    }
  } else {
    // ---- U row: n = bx - 1122 ----
    int n = bx - 34 * 33;
    float* s1 = (float*)&s[0][0];
    float* s2 = s1 + DIM1;
    if (tid < DIM1) s1[tid] = x1[n * DIM1 + tid];
    int t2 = tid - DIM1;
    if (t2 >= 0 && t2 < DIM2) s2[t2] = x2[n * DIM2 + t2];
    __syncthreads();
    for (int k8 = tid; k8 < U_LD / 8; k8 += 256) {
      union { ushort us[8]; uint4 v; } pk;
#pragma unroll
      for (int j = 0; j < 8; ++j) {
        int k = k8 * 8 + j;
        float val = 0.f;
        if (k < K_REAL) { int b = k / DIM2; int c = k - b * DIM2; val = s1[b] * s2[c]; }
        pk.us[j] = f2bf(val);
      }
      *(uint4*)&U[(size_t)n * U_LD + k8 * 8] = pk.v;
    }
  }
}

// ---- main GEMM: 128x128 tile, BK=32, split-K=2, one (a,h) per block.
//      4 waves of 64x64, 16x16x32 MFMA, counted-vmcnt double-buffer.
//      32KB LDS -> 4 blocks/CU -> 16 waves/CU. ----
__global__ __launch_bounds__(256, 4) void gemm_kernel(const ushort* __restrict__ U,
                                                      const ushort* __restrict__ Wt,
                                                      const float* __restrict__ x0,
                                                      float* __restrict__ out) {
  // per buffer: A [128 rows][32 k] = 8KB (ushort 0..4095), B [128 o][32 k] = 8KB (4096..8191)
  __shared__ ushort lds[2][8192];    // 32 KB

  int tid = threadIdx.x;
  int lane = tid & 63;
  int w = tid >> 6;                  // 0..3
  int wr = w >> 1, wc = w & 1;       // wave tile: rows wr*64.., cols wc*64..

  // XCD-aware bijective swizzle: 1056 blocks, 132 per XCD, a-major within XCD.
  int orig = (int)blockIdx.x;
  int logical = (orig & 7) * 132 + (orig >> 3);
  int a = logical >> 5;              // 0..32
  int rem = logical & 31;
  int m = rem >> 1;                  // 0..15
  int h = rem & 1;                   // K-half
  int n0 = m * 128;
  int kk0 = h * 1088;                // 34 steps * 32

  int kblk = lane >> 4;              // 0..3 (16B granule within 64B row)
  int r15 = lane & 15;

  f32x4 acc[4][4];
#pragma unroll
  for (int mi = 0; mi < 4; ++mi)
#pragma unroll
    for (int ni = 0; ni < 4; ++ni)
      acc[mi][ni] = (f32x4){0.f, 0.f, 0.f, 0.f};

  const ushort* WtA = Wt + (size_t)a * OO * U_LD;

  // --- per-thread staging: 4 chunks (2 A + 2 B), pointer-bumped +32 ushorts/step ---
  // chunk c in 0..511: row = c>>2 (64B rows), slot = c&3; LDS dest linear c*16B;
  // global source granule = slot ^ (row&3)  (involution, undone on read side)
  const ushort* pA[2]; const ushort* pB[2];
  int dA[2], dB[2];
#pragma unroll
  for (int i = 0; i < 2; ++i) {
    int c = i * 256 + tid;
    int row = c >> 2;
    int ss = (c & 3) ^ (row & 3);
    pA[i] = U + (size_t)(n0 + row) * U_LD + kk0 + ss * 8;
    dA[i] = c * 8;
    pB[i] = WtA + (size_t)row * U_LD + kk0 + ss * 8;
    dB[i] = 4096 + c * 8;
  }

  auto STAGE = [&](ushort* Lb) {
#pragma unroll
    for (int i = 0; i < 2; ++i) { GLOAD_LDS16(pA[i], Lb + dA[i]); pA[i] += 32; }
#pragma unroll
    for (int i = 0; i < 2; ++i) { GLOAD_LDS16(pB[i], Lb + dB[i]); pB[i] += 32; }
  };

  auto COMPUTE = [&](const ushort* Lb) {
    const char* base = (const char*)Lb;
    bf16x8 af[4], bfr[4];
#pragma unroll
    for (int mi = 0; mi < 4; ++mi) {
      int row = wr * 64 + mi * 16 + r15;
      af[mi] = *(const bf16x8*)(base + row * 64 + (((kblk) ^ (row & 3)) << 4));
    }
#pragma unroll
    for (int ni = 0; ni < 4; ++ni) {
      int row = wc * 64 + ni * 16 + r15;   // o index
      bfr[ni] = *(const bf16x8*)(base + 8192 + row * 64 + (((kblk) ^ (row & 3)) << 4));
    }
    __builtin_amdgcn_s_setprio(1);
#pragma unroll
    for (int mi = 0; mi < 4; ++mi)
#pragma unroll
      for (int ni = 0; ni < 4; ++ni)
        acc[mi][ni] = __builtin_amdgcn_mfma_f32_16x16x32_bf16(af[mi], bfr[ni], acc[mi][ni], 0, 0, 0);
    __builtin_amdgcn_s_setprio(0);
  };

  // prologue: tiles 0,1 in flight (8 loads/thread); wait tile 0 (keep 4 newest)
  STAGE(&lds[0][0]);
  STAGE(&lds[1][0]);
  asm volatile("s_waitcnt vmcnt(4)" ::: "memory");
  __builtin_amdgcn_s_barrier();

  // steady state: 34 tiles, 2x unroll for compile-time buffer index.
  for (int it = 0; it < 16; ++it) {
    COMPUTE(&lds[0][0]);
    __builtin_amdgcn_s_barrier();            // readers done with b0
    STAGE(&lds[0][0]);                       // tile 2it+2 -> b0 (8/thread in flight)
    asm volatile("s_waitcnt vmcnt(4)" ::: "memory");   // b1's tile landed
    __builtin_amdgcn_s_barrier();
    COMPUTE(&lds[1][0]);
    __builtin_amdgcn_s_barrier();
    STAGE(&lds[1][0]);                       // tile 2it+3 -> b1
    asm volatile("s_waitcnt vmcnt(4)" ::: "memory");   // b0's tile landed
    __builtin_amdgcn_s_barrier();
  }
  // tiles 32 (b0, landed) and 33 (b1, in flight)
  COMPUTE(&lds[0][0]);
  asm volatile("s_waitcnt vmcnt(0)" ::: "memory");
  __builtin_amdgcn_s_barrier();
  COMPUTE(&lds[1][0]);

  // epilogue: scale by x0[row, a], atomic-accumulate into out
  int jrow = (lane >> 4) * 4;
#pragma unroll
  for (int mi = 0; mi < 4; ++mi) {
#pragma unroll
    for (int j = 0; j < 4; ++j) {
      int row = n0 + wr * 64 + mi * 16 + jrow + j;
      float s = x0[(size_t)row * DIM0 + a];
#pragma unroll
      for (int ni = 0; ni < 4; ++ni) {
        int col = wc * 64 + ni * 16 + r15;
        atomicAdd(&out[(size_t)row * OO + col], acc[mi][ni][j] * s);
      }
    }
  }
}

// ---- bias + relu, in place on d_out ----
__global__ __launch_bounds__(256) void relu_kernel(float* __restrict__ out,
                                                   const float* __restrict__ bias) {
  int i = blockIdx.x * 256 + threadIdx.x;
  out[i] = fmaxf(out[i] + bias[i & (OO - 1)], 0.f);
}

extern "C" void kernel_launch(void* const* d_in, const int* in_sizes, int n_in,
                              void* d_out, int out_size, void* d_ws, size_t ws_size,
                              hipStream_t stream) {
  const float* x0   = (const float*)d_in[0];
  const float* x1   = (const float*)d_in[1];
  const float* x2   = (const float*)d_in[2];
  const float* W    = (const float*)d_in[3];
  const float* bias = (const float*)d_in[4];
  float* out = (float*)d_out;

  ushort* U  = (ushort*)d_ws;                                   // 2048*2176*2 = 8,912,896 B
  ushort* Wt = (ushort*)((char*)d_ws + (size_t)8912896);        // 33*128*2176*2 = 18,382,848 B

  hipMemsetAsync(d_out, 0, (size_t)NROW * OO * sizeof(float), stream);
  prep_kernel<<<34 * 33 + NROW, 256, 0, stream>>>(x1, x2, W, U, Wt);
  gemm_kernel<<<1056, 256, 0, stream>>>(U, Wt, x0, out);
  relu_kernel<<<(NROW * OO) / 256, 256, 0, stream>>>(out, bias);
}